// Round 6
// baseline (1093.460 us; speedup 1.0000x reference)
//
#include <hip/hip_runtime.h>
#include <math.h>

typedef _Float16 half_t;
typedef __attribute__((ext_vector_type(4))) _Float16 half4;
typedef __attribute__((ext_vector_type(4))) float f32x4;

__device__ __forceinline__ f32x4 MFMA16(half4 a, half4 b, f32x4 c) {
  return __builtin_amdgcn_mfma_f32_16x16x16f16(a, b, c, 0, 0, 0);
}

#if __has_builtin(__builtin_amdgcn_exp2f)
#define EXP2F(x) __builtin_amdgcn_exp2f(x)
#else
#define EXP2F(x) exp2f(x)
#endif

// XOR swizzle for 64-float f32 rows (quad ^= row&15)
__device__ __forceinline__ int SWi(int row, int col) {
  return (row << 6) | (((((col >> 2) ^ row) & 15)) << 2) | (col & 3);
}
__device__ __forceinline__ int SW4i(int row, int q) {
  return (row << 6) | ((((q ^ row) & 15)) << 2);
}
// f16 rows of 64, unit = 4 halves
__device__ __forceinline__ int XH(int t, int k) {
  return (t << 6) | (((((k >> 2) ^ t) & 15)) << 2) | (k & 3);
}
__device__ __forceinline__ int XH4(int t, int k4) {
  return (t << 6) | ((((k4 ^ t) & 15)) << 2);
}

// fast exact-gelu via Abramowitz-Stegun 7.1.26 erf (|err| <= 1.5e-7)
__device__ __forceinline__ float fast_gelu(float v) {
  float x = 0.70710678118654752f * v;
  float ax = fabsf(x);
  float t = 1.0f / fmaf(0.3275911f, ax, 1.0f);
  float poly = t * fmaf(t, fmaf(t, fmaf(t, fmaf(t, 1.061405429f, -1.453152027f),
                                        1.421413741f), -0.284496736f), 0.254829592f);
  float e = EXP2F(-1.4426950408889634f * ax * ax);
  float erfax = fmaf(-poly, e, 1.0f);
  float er = __builtin_copysignf(erfax, x);
  return 0.5f * v * (1.0f + er);
}

// ---------------------------------------------------------------------------
// prepack: all weights -> f16 MFMA fragment order. h4 slot layout:
//   WQP[0,3072) WOP[3072,4096) W1P[4096,8192) W2P[8192,12288)
//   WcP[12288,16128) PwP[16128,18688)
// fragment: slot (unit*64+ln) = M[tile*16 + (ln&15)][ks*16 + (ln>>4)*4 + r]
// ---------------------------------------------------------------------------
__global__ void k_prepack(const float* __restrict__ conv_w,
                          const float* __restrict__ proj_w,
                          const float* __restrict__ Wqkv,
                          const float* __restrict__ Wo,
                          const float* __restrict__ W1,
                          const float* __restrict__ W2,
                          half_t* __restrict__ dst) {
  int id = blockIdx.x * 512 + threadIdx.x;
  if (id >= 18688) return;
  int ln = id & 63, unit = id >> 6;
  int li = ln & 15, gq = (ln >> 4) * 4;
  float v[4];
  if (unit < 48) {                       // Wqkv [192][64]
    int rt = unit >> 2, ks = unit & 3;
    const float* s = &Wqkv[(rt * 16 + li) * 64 + ks * 16 + gq];
#pragma unroll
    for (int r = 0; r < 4; ++r) v[r] = s[r];
  } else if (unit < 64) {                // Wo [64][64]
    int u = unit - 48, ct = u >> 2, h = u & 3;
    const float* s = &Wo[(ct * 16 + li) * 64 + h * 16 + gq];
#pragma unroll
    for (int r = 0; r < 4; ++r) v[r] = s[r];
  } else if (unit < 128) {               // W1 [256][64]
    int u = unit - 64, rt = u >> 2, ks = u & 3;
    const float* s = &W1[(rt * 16 + li) * 64 + ks * 16 + gq];
#pragma unroll
    for (int r = 0; r < 4; ++r) v[r] = s[r];
  } else if (unit < 192) {               // W2 [64][256]
    int u = unit - 128, rt = u >> 4, ks = u & 15;
    const float* s = &W2[(rt * 16 + li) * 256 + ks * 16 + gq];
#pragma unroll
    for (int r = 0; r < 4; ++r) v[r] = s[r];
  } else if (unit < 252) {               // conv_w [150][81] pad to [160][96]
    int u = unit - 192, ct = u / 6, ks = u - ct * 6;
    int row = ct * 16 + li;
#pragma unroll
    for (int r = 0; r < 4; ++r) {
      int col = ks * 16 + gq + r;
      v[r] = (row < 150 && col < 81) ? conv_w[row * 81 + col] : 0.f;
    }
  } else {                               // proj_w [64][150] pad to [64][160]
    int u = unit - 252, dt = u / 10, ct = u - dt * 10;
#pragma unroll
    for (int r = 0; r < 4; ++r) {
      int col = ct * 16 + gq + r;
      v[r] = (col < 150) ? proj_w[(dt * 16 + li) * 150 + col] : 0.f;
    }
  }
  half4 o;
#pragma unroll
  for (int r = 0; r < 4; ++r) o[r] = (half_t)v[r];
  ((half4*)dst)[id] = o;
}

// ---------------------------------------------------------------------------
// conv1 (1->150, k9 s2 p4) + gelu + 1x1 proj via chained MFMA, register im2col
// weights read direct from global (L2-resident, shared by all blocks).
// output staged per-wave in LDS, drained row-contiguous (coalesced 256B).
// ---------------------------------------------------------------------------
__global__ __launch_bounds__(512, 4) void k_conv(
    const float* __restrict__ x, const half_t* __restrict__ WcP,
    const half_t* __restrict__ PwP, const float* __restrict__ proj_b,
    float* __restrict__ tokens) {
  __shared__ float xs[1260];           // 35 x 36 zero-padded image
  __shared__ float outst[8 * 1088];    // 8 waves x 16 x 68 staging

  const int b = blockIdx.x, tid = threadIdx.x;
  const int wv = tid >> 6, ln = tid & 63, g = ln >> 4, li = ln & 15;
  const size_t base = (size_t)b * 12544;

  for (int i = tid; i < 1260; i += 512) xs[i] = 0.f;
  __syncthreads();
  for (int i = tid; i < 784; i += 512) {
    int r = i / 28, c = i - r * 28;
    xs[(r + 4) * 36 + c + 4] = x[b * 784 + i];
  }
  __syncthreads();

  float4 pb4[4];
#pragma unroll
  for (int dt = 0; dt < 4; ++dt) pb4[dt] = *(const float4*)&proj_b[dt * 16 + g * 4];

  for (int pt = wv; pt < 13; pt += 8) {
    int pp = pt * 16 + li;
    int pc = (pp < 196) ? pp : 195;
    int oy = pc / 14, ox = pc - oy * 14;
    int pbase = (oy * 2) * 36 + ox * 2;
    // register im2col: lane holds taps ks*16+g*4+r of patch pp
    half4 bf[6];
#pragma unroll
    for (int ks = 0; ks < 6; ++ks) {
#pragma unroll
      for (int r = 0; r < 4; ++r) {
        int tap = ks * 16 + g * 4 + r;   // 0..95
        float v = 0.f;
        if (ks < 5) {
          int ky = tap / 9;
          v = xs[pbase + ky * 27 + tap];
        } else if (tap == 80) {
          v = xs[pbase + 8 * 27 + 80];
        }
        bf[ks][r] = (half_t)v;
      }
    }
    // GEMM1: conv channels (weights direct from global/L2), gelu in-register
    half4 hf[10];
#pragma unroll
    for (int ct = 0; ct < 10; ++ct) {
      f32x4 acc = {0.f, 0.f, 0.f, 0.f};
#pragma unroll
      for (int ks = 0; ks < 6; ++ks)
        acc = MFMA16(((const half4*)WcP)[(ct * 6 + ks) * 64 + ln], bf[ks], acc);
#pragma unroll
      for (int r = 0; r < 4; ++r) hf[ct][r] = (half_t)fast_gelu(acc[r]);
    }
    // GEMM2: proj to d=64, stage to wave-private LDS tile
#pragma unroll
    for (int dt = 0; dt < 4; ++dt) {
      f32x4 zz = {0.f, 0.f, 0.f, 0.f};
#pragma unroll
      for (int ct = 0; ct < 10; ++ct)
        zz = MFMA16(((const half4*)PwP)[(dt * 10 + ct) * 64 + ln], hf[ct], zz);
      float4 o;
      o.x = zz[0] + pb4[dt].x; o.y = zz[1] + pb4[dt].y;
      o.z = zz[2] + pb4[dt].z; o.w = zz[3] + pb4[dt].w;
      *(float4*)&outst[wv * 1088 + li * 68 + dt * 16 + g * 4] = o;
    }
    // drain: row-contiguous (intra-wave LDS order is architectural)
#pragma unroll
    for (int rep = 0; rep < 4; ++rep) {
      int r4 = rep * 64 + ln;
      int row = r4 >> 4, q = r4 & 15;
      int p = pt * 16 + row;
      if (p < 196) {
        *(float4*)&tokens[base + (size_t)p * 64 + q * 4] =
            *(const float4*)&outst[wv * 1088 + row * 68 + q * 4];
      }
    }
  }
}

// ---------------------------------------------------------------------------
// attention: LN1 (fused) -> QKV -> attn (2 head-pass) -> +Wo+bo residual RMW.
// epilogue stages z-fragments in LDS (aliased over Kb/VT) -> coalesced RMW.
// ---------------------------------------------------------------------------
__global__ __launch_bounds__(512, 4) void k_attn(
    float* __restrict__ tokens, const float* __restrict__ ln1_g,
    const float* __restrict__ ln1_b, const half_t* __restrict__ WQP,
    const float* __restrict__ bqkv, const half_t* __restrict__ WOP,
    const float* __restrict__ bo) {
  __shared__ __align__(16) char pool[56832];
  half_t* Xh = (half_t*)pool;                 // 26,624B: t1 f16 swizzled
  half_t* Kb = (half_t*)(pool + 26624);       // 16,640B: K, 2 heads [208][20]
  half_t* VT = (half_t*)(pool + 43264);       // 13,568B: V^T, 2 heads [16][212]
  float* OS = (float*)(pool + 26624);         // epilogue staging (aliases Kb/VT)

  const int b = blockIdx.x, tid = threadIdx.x;
  const int wv = tid >> 6, ln = tid & 63, g = ln >> 4, li = ln & 15;
  const size_t base = (size_t)b * 12544;

  // fused LN1: coalesced row read + butterfly stats -> Xh
  {
    float gg = ln1_g[ln], bb = ln1_b[ln];
    for (int k = 0; k < 25; ++k) {
      int t = wv + 8 * k;
      if (t < 196) {
        float v = tokens[base + t * 64 + ln];
        float s = v;
#pragma unroll
        for (int d = 1; d < 64; d <<= 1) s += __shfl_xor(s, d, 64);
        float mu = s * 0.015625f;
        float dd = v - mu, s2 = dd * dd;
#pragma unroll
        for (int d = 1; d < 64; d <<= 1) s2 += __shfl_xor(s2, d, 64);
        float rs = rsqrtf(s2 * 0.015625f + 1e-5f);
        Xh[XH(t, ln)] = (half_t)(dd * rs * gg + bb);
      }
    }
    for (int i = tid; i < 768; i += 512) Xh[XH(196 + (i >> 6), i & 63)] = (half_t)0.f;
  }
  __syncthreads();

  f32x4 z[2][4];
#pragma unroll
  for (int qi = 0; qi < 2; ++qi)
#pragma unroll
    for (int ct = 0; ct < 4; ++ct) z[qi][ct] = f32x4{0.f, 0.f, 0.f, 0.f};

  for (int p = 0; p < 2; ++p) {          // head pairs {2p, 2p+1}
    {
      // K/V for this pass: wave -> r-tile (K h, K h+1, V h, V h+1)
      int rt4 = wv & 3, hh = rt4 & 1;
      bool isK = rt4 < 2;
      int rtg = (isK ? 4 : 8) + 2 * p + hh;
      half4 af[4];
#pragma unroll
      for (int ks = 0; ks < 4; ++ks) af[ks] = ((const half4*)WQP)[(rtg * 4 + ks) * 64 + ln];
      float bias[4];
      int brow = (isK ? 64 : 128) + (2 * p + hh) * 16 + g * 4;
#pragma unroll
      for (int r = 0; r < 4; ++r) bias[r] = bqkv[brow + r];
      int ta = (wv < 4) ? 0 : 7, tz = (wv < 4) ? 7 : 13;
      for (int tt = ta; tt < tz; ++tt) {
        int trow = tt * 16 + li;
        f32x4 acc = {0.f, 0.f, 0.f, 0.f};
#pragma unroll
        for (int ks = 0; ks < 4; ++ks)
          acc = MFMA16(af[ks], *(const half4*)&Xh[XH4(trow, ks * 4 + g)], acc);
        if (isK) {
#pragma unroll
          for (int r = 0; r < 4; ++r)
            Kb[(hh * 208 + trow) * 20 + g * 4 + r] = (half_t)(acc[r] + bias[r]);
        } else {
#pragma unroll
          for (int r = 0; r < 4; ++r)
            VT[(hh * 16 + g * 4 + r) * 212 + trow] = (half_t)(acc[r] + bias[r]);
        }
      }
    }
    // Q fragments for the pass's 2 heads (scale folds 1/4 * log2(e))
    half4 qf[2][2];
#pragma unroll
    for (int hh = 0; hh < 2; ++hh) {
      half4 aq[4];
#pragma unroll
      for (int ks = 0; ks < 4; ++ks)
        aq[ks] = ((const half4*)WQP)[((2 * p + hh) * 4 + ks) * 64 + ln];
      float qb[4];
#pragma unroll
      for (int r = 0; r < 4; ++r) qb[r] = bqkv[(2 * p + hh) * 16 + g * 4 + r];
#pragma unroll
      for (int qi = 0; qi < 2; ++qi) {
        int qt = wv + 8 * qi;
        if (qt < 13) {
          f32x4 acc = {0.f, 0.f, 0.f, 0.f};
#pragma unroll
          for (int ks = 0; ks < 4; ++ks)
            acc = MFMA16(aq[ks], *(const half4*)&Xh[XH4(qt * 16 + li, ks * 4 + g)], acc);
#pragma unroll
          for (int r = 0; r < 4; ++r)
            qf[qi][hh][r] = (half_t)((acc[r] + qb[r]) * 0.36067376022224085f);
        }
      }
    }
    __syncthreads();
    // attention for the 2 heads; exp+PV fused (P consumed on the fly)
#pragma unroll
    for (int qi = 0; qi < 2; ++qi) {
      int qt = wv + 8 * qi;
      if (qt < 13) {
#pragma unroll
        for (int hh = 0; hh < 2; ++hh) {
          f32x4 s[13];
#pragma unroll
          for (int nt = 0; nt < 13; ++nt) {
            f32x4 zz = {0.f, 0.f, 0.f, 0.f};
            s[nt] = MFMA16(*(const half4*)&Kb[(hh * 208 + nt * 16 + li) * 20 + g * 4],
                           qf[qi][hh], zz);
          }
          if (g > 0) { s[12][0] = -3e38f; s[12][1] = -3e38f; s[12][2] = -3e38f; s[12][3] = -3e38f; }
          float m = -3e38f;
#pragma unroll
          for (int nt = 0; nt < 13; ++nt)
#pragma unroll
            for (int r = 0; r < 4; ++r) m = fmaxf(m, s[nt][r]);
          m = fmaxf(m, __shfl_xor(m, 16, 64));
          m = fmaxf(m, __shfl_xor(m, 32, 64));
          float es = 0.f;
          f32x4 oa = {0.f, 0.f, 0.f, 0.f}, ob = {0.f, 0.f, 0.f, 0.f};
#pragma unroll
          for (int nt = 0; nt < 13; ++nt) {
            half4 pf;
#pragma unroll
            for (int r = 0; r < 4; ++r) {
              float e = EXP2F(s[nt][r] - m);
              es += e;
              pf[r] = (half_t)e;
            }
            half4 va = *(const half4*)&VT[(hh * 16 + li) * 212 + nt * 16 + g * 4];
            if (nt & 1) ob = MFMA16(va, pf, ob);
            else oa = MFMA16(va, pf, oa);
          }
          es += __shfl_xor(es, 16, 64);
          es += __shfl_xor(es, 32, 64);
          float inv = 1.0f / es;
          half4 of;
#pragma unroll
          for (int r = 0; r < 4; ++r) of[r] = (half_t)((oa[r] + ob[r]) * inv);
          int hglob = 2 * p + hh;
#pragma unroll
          for (int ct = 0; ct < 4; ++ct) {
            half4 wf = ((const half4*)WOP)[(ct * 4 + hglob) * 64 + ln];
            z[qi][ct] = MFMA16(wf, of, z[qi][ct]);
          }
        }
      }
    }
    __syncthreads();
  }
  // epilogue: stage z in LDS (over Kb/VT) then coalesced residual RMW + bo.
  // 4 rounds of up to 4 q-tiles (17,408B <= 30,208B available).
  float4 bo4 = *(const float4*)&bo[(tid & 15) * 4];
  for (int rd = 0; rd < 4; ++rd) {
#pragma unroll
    for (int qi = 0; qi < 2; ++qi) {
      int qt = wv + 8 * qi;
      if (qt < 13 && (qt >> 2) == rd) {
        int slot = qt & 3;
#pragma unroll
        for (int ct = 0; ct < 4; ++ct) {
          float4 o;
          o.x = z[qi][ct][0]; o.y = z[qi][ct][1];
          o.z = z[qi][ct][2]; o.w = z[qi][ct][3];
          *(float4*)&OS[slot * 1088 + li * 68 + ct * 16 + g * 4] = o;
        }
      }
    }
    __syncthreads();
    int nelem = (rd < 3) ? 1024 : 256;   // 4 tiles / 1 tile x 256 float4-units
    for (int i = tid; i < nelem; i += 512) {
      int slot = i >> 8, rw = (i >> 4) & 15, q = i & 15;
      int t = (rd * 4 + slot) * 16 + rw;
      if (t < 196) {
        float4 v = *(const float4*)&OS[slot * 1088 + rw * 68 + q * 4];
        float4 t4 = *(const float4*)&tokens[base + (size_t)t * 64 + q * 4];
        t4.x += v.x + bo4.x; t4.y += v.y + bo4.y;
        t4.z += v.z + bo4.z; t4.w += v.w + bo4.w;
        *(float4*)&tokens[base + (size_t)t * 64 + q * 4] = t4;
      }
    }
    __syncthreads();
  }
}

// ---------------------------------------------------------------------------
// FFN: LN2 (fused) -> gelu(t2@W1^T+b1)@W2^T + b2, residual RMW to global.
// epilogue stages facc in LDS (aliased over Xh/Hb) -> coalesced RMW.
// 69,632 B dynamic LDS -> 2 blocks/CU
// ---------------------------------------------------------------------------
__global__ __launch_bounds__(512, 4) void k_ffn(
    float* __restrict__ tokens, const float* __restrict__ ln2_g,
    const float* __restrict__ ln2_b, const half_t* __restrict__ W1P,
    const float* __restrict__ b1, const half_t* __restrict__ W2P,
    const float* __restrict__ b2) {
  extern __shared__ half_t fsm[];
  half_t* Xh = fsm;                       // 13312 halves
  half_t* Hb = fsm + 13312;               // 13312 halves
  half4* W1S = (half4*)(fsm + 26624);     // 1024 frags
  half4* W2S = (half4*)(fsm + 26624 + 4096);
  float* OS = (float*)fsm;                // epilogue staging [196][68] floats

  const int b = blockIdx.x, tid = threadIdx.x;
  const int wv = tid >> 6, ln = tid & 63, g = ln >> 4, li = ln & 15;
  const size_t base = (size_t)b * 12544;

  {
    float gg = ln2_g[ln], bb = ln2_b[ln];
    for (int k = 0; k < 25; ++k) {
      int t = wv + 8 * k;
      if (t < 196) {
        float v = tokens[base + t * 64 + ln];
        float s = v;
#pragma unroll
        for (int d = 1; d < 64; d <<= 1) s += __shfl_xor(s, d, 64);
        float mu = s * 0.015625f;
        float dd = v - mu, s2 = dd * dd;
#pragma unroll
        for (int d = 1; d < 64; d <<= 1) s2 += __shfl_xor(s2, d, 64);
        float rs = rsqrtf(s2 * 0.015625f + 1e-5f);
        Xh[XH(t, ln)] = (half_t)(dd * rs * gg + bb);
      }
    }
    for (int i = tid; i < 768; i += 512) Xh[XH(196 + (i >> 6), i & 63)] = (half_t)0.f;
  }
  __syncthreads();

  f32x4 facc[7];
#pragma unroll
  for (int j = 0; j < 7; ++j) facc[j] = f32x4{0.f, 0.f, 0.f, 0.f};

  for (int ch = 0; ch < 4; ++ch) {
    for (int i = tid; i < 1024; i += 512) W1S[i] = ((const half4*)W1P)[ch * 1024 + i];
    for (int i = tid; i < 1024; i += 512) {
      int nt = i >> 8, kl = (i >> 6) & 3, l2 = i & 63;
      W2S[i] = ((const half4*)W2P)[(nt * 16 + ch * 4 + kl) * 64 + l2];
    }
    __syncthreads();
    // H = gelu(t2 @ W1^T + b1)
#pragma unroll
    for (int j = 0; j < 7; ++j) {
      int u = wv + 8 * j;
      if (u < 52) {
        int mt = u >> 2, nt = u & 3;
        f32x4 acc = {0.f, 0.f, 0.f, 0.f};
#pragma unroll
        for (int ks = 0; ks < 4; ++ks)
          acc = MFMA16(*(const half4*)&Xh[XH4(mt * 16 + li, ks * 4 + g)],
                       W1S[(nt * 4 + ks) * 64 + ln], acc);
        float bb = b1[ch * 64 + nt * 16 + li];
#pragma unroll
        for (int r = 0; r < 4; ++r)
          Hb[XH(mt * 16 + g * 4 + r, nt * 16 + li)] = (half_t)fast_gelu(acc[r] + bb);
      }
    }
    __syncthreads();
    // facc += H @ W2^T
#pragma unroll
    for (int j = 0; j < 7; ++j) {
      int u = wv + 8 * j;
      if (u < 52) {
        int mt = u >> 2, nt = u & 3;
#pragma unroll
        for (int ks = 0; ks < 4; ++ks)
          facc[j] = MFMA16(*(const half4*)&Hb[XH4(mt * 16 + li, ks * 4 + g)],
                           W2S[(nt * 4 + ks) * 64 + ln], facc[j]);
      }
    }
    __syncthreads();
  }
  // epilogue: stage all facc tiles into OS [196][68], then coalesced RMW + b2
#pragma unroll
  for (int j = 0; j < 7; ++j) {
    int u = wv + 8 * j;
    if (u < 52) {
      int mt = u >> 2, nt = u & 3;
#pragma unroll
      for (int r = 0; r < 4; ++r) {
        int t = mt * 16 + g * 4 + r;
        if (t < 196) OS[t * 68 + nt * 16 + li] = facc[j][r];
      }
    }
  }
  __syncthreads();
  float4 b2v = *(const float4*)&b2[(tid & 15) * 4];
  for (int i = tid; i < 3136; i += 512) {
    int t = i >> 4, q = i & 15;
    float4 v = *(const float4*)&OS[t * 68 + q * 4];
    float4 t4 = *(const float4*)&tokens[base + (size_t)t * 64 + q * 4];
    t4.x += v.x + b2v.x; t4.y += v.y + b2v.y;
    t4.z += v.z + b2v.z; t4.w += v.w + b2v.w;
    *(float4*)&tokens[base + (size_t)t * 64 + q * 4] = t4;
  }
}

// ---------------------------------------------------------------------------
// slots: fused final-LN at load + slot attention + spmask + classifier (f32)
// ---------------------------------------------------------------------------
__global__ __launch_bounds__(256) void k_slots(
    const float* __restrict__ tokens, const float* __restrict__ slot_q,
    const float* __restrict__ cls_w, const float* __restrict__ cls_b,
    const int* __restrict__ use_spmask_p, const int* __restrict__ grid_p,
    float* __restrict__ out, const float* __restrict__ tln_g,
    const float* __restrict__ tln_b) {
  __shared__ float TOK[12544];
  __shared__ float Abuf[12 * 196];
  __shared__ float SQS[12 * 64];
  __shared__ float INV[196];
  __shared__ float VV[64];
  __shared__ float Pv[12];
  __shared__ float M2[12];
  __shared__ float ISN[12];
  __shared__ float ZS[2];

  const int b = blockIdx.x, tid = threadIdx.x;
  const size_t base = (size_t)b * 12544;
  (void)grid_p;
  const int wv4 = tid >> 6, ln = tid & 63;

  // fused final-LN load
  {
    float tg = tln_g[ln], tb = tln_b[ln];
    for (int k = 0; k < 49; ++k) {
      int t = wv4 + 4 * k;
      float v = tokens[base + t * 64 + ln];
      float s = v;
#pragma unroll
      for (int d = 1; d < 64; d <<= 1) s += __shfl_xor(s, d, 64);
      float mu = s * 0.015625f;
      float dd = v - mu, s2 = dd * dd;
#pragma unroll
      for (int d = 1; d < 64; d <<= 1) s2 += __shfl_xor(s2, d, 64);
      float rs = rsqrtf(s2 * 0.015625f + 1e-5f);
      TOK[SWi(t, ln)] = dd * rs * tg + tb;
    }
  }
  __syncthreads();
  if (tid < 196) {
    float ss = 0.f;
#pragma unroll
    for (int q = 0; q < 16; ++q) {
      float4 v = *(const float4*)&TOK[SW4i(tid, q)];
      ss += v.x * v.x + v.y * v.y + v.z * v.z + v.w * v.w;
    }
    INV[tid] = 1.0f / fmaxf(sqrtf(ss), 1e-12f);
  }
  if (tid < 192) {
    int m = tid >> 4, l = tid & 15;
    float ss = 0.f;
#pragma unroll
    for (int c = l; c < 64; c += 16) {
      float v = slot_q[m * 64 + c];
      ss += v * v;
    }
#pragma unroll
    for (int mm = 8; mm; mm >>= 1) ss += __shfl_xor(ss, mm, 64);
    float invq = 1.0f / fmaxf(sqrtf(ss), 1e-12f);
#pragma unroll
    for (int c = l; c < 64; c += 16) SQS[m * 64 + c] = slot_q[m * 64 + c] * invq;
  }
  __syncthreads();
  for (int i = tid; i < 2352; i += 256) {
    int m = i / 196, n = i - m * 196;
    float d = 0.f;
#pragma unroll
    for (int q = 0; q < 16; ++q) {
      float4 tv = *(const float4*)&TOK[SW4i(n, q)];
      float4 sv = *(const float4*)&SQS[m * 64 + q * 4];
      d += tv.x * sv.x + tv.y * sv.y + tv.z * sv.z + tv.w * sv.w;
    }
    Abuf[i] = d * INV[n] * 0.125f;
  }
  __syncthreads();
  const int use_spmask = *use_spmask_p;
  if (tid < 192) {
    int m = tid >> 4, l = tid & 15;
    float* Am = Abuf + m * 196;
    float mx = -1e30f;
    for (int n = l; n < 196; n += 16) mx = fmaxf(mx, Am[n]);
#pragma unroll
    for (int mm = 8; mm; mm >>= 1) mx = fmaxf(mx, __shfl_xor(mx, mm, 64));
    float se = 0.f, mc0 = 0.f, mc1 = 0.f, mc2 = 0.f, mc3 = 0.f;
    for (int n = l; n < 196; n += 16) {
      float e = __expf(Am[n] - mx);
      Am[n] = e;
      se += e;
      int yy = n / 14, xx = n - yy * 14;
      int cell = ((yy >= 7) ? 2 : 0) + ((xx >= 7) ? 1 : 0);
      mc0 += (cell == 0) ? e : 0.f;
      mc1 += (cell == 1) ? e : 0.f;
      mc2 += (cell == 2) ? e : 0.f;
      mc3 += (cell == 3) ? e : 0.f;
    }
#pragma unroll
    for (int mm = 8; mm; mm >>= 1) {
      se += __shfl_xor(se, mm, 64);
      mc0 += __shfl_xor(mc0, mm, 64);
      mc1 += __shfl_xor(mc1, mm, 64);
      mc2 += __shfl_xor(mc2, mm, 64);
      mc3 += __shfl_xor(mc3, mm, 64);
    }
    float invse = 1.0f / se;
    if (use_spmask) {
      int g1 = 0; float bv1 = mc0;
      if (mc1 > bv1) { bv1 = mc1; g1 = 1; }
      if (mc2 > bv1) { bv1 = mc2; g1 = 2; }
      if (mc3 > bv1) { bv1 = mc3; g1 = 3; }
      int g2 = -1; float bv2 = -1e30f;
      if (g1 != 0 && mc0 > bv2) { bv2 = mc0; g2 = 0; }
      if (g1 != 1 && mc1 > bv2) { bv2 = mc1; g2 = 1; }
      if (g1 != 2 && mc2 > bv2) { bv2 = mc2; g2 = 2; }
      if (g1 != 3 && mc3 > bv2) { bv2 = mc3; g2 = 3; }
      float sacc = 0.f;
      for (int n = l; n < 196; n += 16) {
        float a = Am[n] * invse;
        Am[n] = a;
        int yy = n / 14, xx = n - yy * 14;
        int cell = ((yy >= 7) ? 2 : 0) + ((xx >= 7) ? 1 : 0);
        sacc += (cell == g1 || cell == g2) ? a : 0.f;
      }
#pragma unroll
      for (int mm = 8; mm; mm >>= 1) sacc += __shfl_xor(sacc, mm, 64);
      float invs = 1.0f / fmaxf(sacc, 1e-8f);
      float m2acc = 0.f;
      for (int n = l; n < 196; n += 16) {
        int yy = n / 14, xx = n - yy * 14;
        int cell = ((yy >= 7) ? 2 : 0) + ((xx >= 7) ? 1 : 0);
        float a = (cell == g1 || cell == g2) ? (Am[n] * invs) : 0.f;
        Am[n] = a;
        m2acc += a;
      }
#pragma unroll
      for (int mm = 8; mm; mm >>= 1) m2acc += __shfl_xor(m2acc, mm, 64);
      if (l == 0) M2[m] = m2acc;
    } else {
      for (int n = l; n < 196; n += 16) Am[n] *= invse;
      if (l == 0) M2[m] = mx + logf(se);
    }
  }
  __syncthreads();
  if (tid == 0) {
    float mean = 0.f;
    for (int m = 0; m < 12; ++m) mean += M2[m];
    mean *= (1.0f / 12.0f);
    float zmax = -1e30f;
    for (int m = 0; m < 12; ++m) {
      float z = (M2[m] - mean) * 2.0f;
      Pv[m] = z;
      zmax = fmaxf(zmax, z);
    }
    float seP = 0.f;
    for (int m = 0; m < 12; ++m) {
      float e = __expf(Pv[m] - zmax);
      Pv[m] = e;
      seP += e;
    }
    float invP = 1.0f / seP;
    float sump = 0.f;
    for (int m = 0; m < 12; ++m) {
      float p = Pv[m] * invP;
      Pv[m] = p;
      sump += p;
    }
    ZS[0] = sump;
  }
  __syncthreads();
  for (int i = tid; i < 768; i += 256) {
    int m = i >> 6, c = i & 63;
    float a2 = 0.f;
    const float* Am = Abuf + m * 196;
    for (int n = 0; n < 196; ++n) a2 += Am[n] * TOK[SWi(n, c)];
    SQS[m * 64 + c] = a2;
  }
  __syncthreads();
  if (tid < 192) {
    int m = tid >> 4, l = tid & 15;
    float ss = 0.f;
#pragma unroll
    for (int c = l; c < 64; c += 16) {
      float v = SQS[m * 64 + c];
      ss += v * v;
    }
#pragma unroll
    for (int mm = 8; mm; mm >>= 1) ss += __shfl_xor(ss, mm, 64);
    if (l == 0) ISN[m] = 1.0f / fmaxf(sqrtf(ss), 1e-12f);
  }
  __syncthreads();
  if (tid < 64) {
    float v = 0.f;
#pragma unroll
    for (int m = 0; m < 12; ++m) v += Pv[m] * ISN[m] * SQS[m * 64 + tid];
    VV[tid] = v;
  }
  __syncthreads();
  if (tid < 47) {
    float a2 = 0.f;
#pragma unroll
    for (int q = 0; q < 16; ++q) {
      float4 w = *(const float4*)&cls_w[tid * 64 + q * 4];
      float4 v = *(const float4*)&VV[q * 4];
      a2 += w.x * v.x + w.y * v.y + w.z * v.z + w.w * v.w;
    }
    out[(size_t)b * 47 + tid] = a2 + cls_b[tid] * ZS[0];
  }
}

// ---------------------------------------------------------------------------
extern "C" void kernel_launch(void* const* d_in, const int* in_sizes, int n_in,
                              void* d_out, int out_size, void* d_ws, size_t ws_size,
                              hipStream_t stream) {
  (void)n_in; (void)out_size; (void)ws_size;
  const float* x      = (const float*)d_in[0];
  const float* conv_w = (const float*)d_in[1];
  const float* proj_w = (const float*)d_in[2];
  const float* proj_b = (const float*)d_in[3];
  const float* ln1_g  = (const float*)d_in[4];
  const float* ln1_b  = (const float*)d_in[5];
  const float* Wqkv   = (const float*)d_in[6];
  const float* bqkv   = (const float*)d_in[7];
  const float* Wo     = (const float*)d_in[8];
  const float* bo     = (const float*)d_in[9];
  const float* ln2_g  = (const float*)d_in[10];
  const float* ln2_b  = (const float*)d_in[11];
  const float* W1     = (const float*)d_in[12];
  const float* b1     = (const float*)d_in[13];
  const float* W2     = (const float*)d_in[14];
  const float* b2     = (const float*)d_in[15];
  const float* tln_g  = (const float*)d_in[16];
  const float* tln_b  = (const float*)d_in[17];
  const float* slot_q = (const float*)d_in[18];
  const float* cls_w  = (const float*)d_in[19];
  const float* cls_b  = (const float*)d_in[20];
  const int* use_spm  = (const int*)d_in[21];
  const int* spgrid   = (const int*)d_in[22];

  const int B = in_sizes[0] / 784;
  half_t* wsh = (half_t*)d_ws;
  const half_t* WQP = wsh;                     // h4 slots, see k_prepack
  const half_t* WOP = wsh + 3072 * 4;
  const half_t* W1P = wsh + 4096 * 4;
  const half_t* W2P = wsh + 8192 * 4;
  const half_t* WcP = wsh + 12288 * 4;
  const half_t* PwP = wsh + 16128 * 4;
  float* tokens = (float*)((char*)d_ws + 163840);

  k_prepack<<<37, 512, 0, stream>>>(conv_w, proj_w, Wqkv, Wo, W1, W2, wsh);
  k_conv<<<B, 512, 0, stream>>>(x, WcP, PwP, proj_b, tokens);
  k_attn<<<B, 512, 0, stream>>>(tokens, ln1_g, ln1_b, WQP, bqkv, WOP, bo);
  (void)hipFuncSetAttribute((const void*)k_ffn,
                            hipFuncAttributeMaxDynamicSharedMemorySize, 69632);
  k_ffn<<<B, 512, 69632, stream>>>(tokens, ln2_g, ln2_b, W1P, b1, W2P, b2);
  k_slots<<<B, 256, 0, stream>>>(tokens, slot_q, cls_w, cls_b, use_spm, spgrid,
                                 (float*)d_out, tln_g, tln_b);
}

// Round 7
// 526.045 us; speedup vs baseline: 2.0786x; 2.0786x over previous
//
#include <hip/hip_runtime.h>
#include <math.h>

typedef _Float16 half_t;
typedef __attribute__((ext_vector_type(4))) _Float16 half4;
typedef __attribute__((ext_vector_type(4))) float f32x4;

__device__ __forceinline__ f32x4 MFMA16(half4 a, half4 b, f32x4 c) {
  return __builtin_amdgcn_mfma_f32_16x16x16f16(a, b, c, 0, 0, 0);
}

#if __has_builtin(__builtin_amdgcn_exp2f)
#define EXP2F(x) __builtin_amdgcn_exp2f(x)
#else
#define EXP2F(x) exp2f(x)
#endif

// XOR swizzle for 64-float f32 rows (quad ^= row&15) — used by k_slots
__device__ __forceinline__ int SWi(int row, int col) {
  return (row << 6) | (((((col >> 2) ^ row) & 15)) << 2) | (col & 3);
}
__device__ __forceinline__ int SW4i(int row, int q) {
  return (row << 6) | ((((q ^ row) & 15)) << 2);
}
// f16 rows of 64, unit = 4 halves
__device__ __forceinline__ int XH(int t, int k) {
  return (t << 6) | (((((k >> 2) ^ t) & 15)) << 2) | (k & 3);
}
__device__ __forceinline__ int XH4(int t, int k4) {
  return (t << 6) | ((((k4 ^ t) & 15)) << 2);
}

// fast exact-gelu via Abramowitz-Stegun 7.1.26 erf (|err| <= 1.5e-7)
__device__ __forceinline__ float fast_gelu(float v) {
  float x = 0.70710678118654752f * v;
  float ax = fabsf(x);
  float t = 1.0f / fmaf(0.3275911f, ax, 1.0f);
  float poly = t * fmaf(t, fmaf(t, fmaf(t, fmaf(t, 1.061405429f, -1.453152027f),
                                        1.421413741f), -0.284496736f), 0.254829592f);
  float e = EXP2F(-1.4426950408889634f * ax * ax);
  float erfax = fmaf(-poly, e, 1.0f);
  float er = __builtin_copysignf(erfax, x);
  return 0.5f * v * (1.0f + er);
}

// ---------------------------------------------------------------------------
// prepack: all weights -> f16 MFMA fragment order. h4 slot layout:
//   WQP[0,3072) WOP[3072,4096) W1P[4096,8192) W2P[8192,12288)
//   WcP[12288,16128) PwP[16128,18688)
// fragment: slot (unit*64+ln) = M[tile*16 + (ln&15)][ks*16 + (ln>>4)*4 + r]
// ---------------------------------------------------------------------------
__global__ void k_prepack(const float* __restrict__ conv_w,
                          const float* __restrict__ proj_w,
                          const float* __restrict__ Wqkv,
                          const float* __restrict__ Wo,
                          const float* __restrict__ W1,
                          const float* __restrict__ W2,
                          half_t* __restrict__ dst) {
  int id = blockIdx.x * 512 + threadIdx.x;
  if (id >= 18688) return;
  int ln = id & 63, unit = id >> 6;
  int li = ln & 15, gq = (ln >> 4) * 4;
  float v[4];
  if (unit < 48) {                       // Wqkv [192][64]
    int rt = unit >> 2, ks = unit & 3;
    const float* s = &Wqkv[(rt * 16 + li) * 64 + ks * 16 + gq];
#pragma unroll
    for (int r = 0; r < 4; ++r) v[r] = s[r];
  } else if (unit < 64) {                // Wo [64][64]
    int u = unit - 48, ct = u >> 2, h = u & 3;
    const float* s = &Wo[(ct * 16 + li) * 64 + h * 16 + gq];
#pragma unroll
    for (int r = 0; r < 4; ++r) v[r] = s[r];
  } else if (unit < 128) {               // W1 [256][64]
    int u = unit - 64, rt = u >> 2, ks = u & 3;
    const float* s = &W1[(rt * 16 + li) * 64 + ks * 16 + gq];
#pragma unroll
    for (int r = 0; r < 4; ++r) v[r] = s[r];
  } else if (unit < 192) {               // W2 [64][256]
    int u = unit - 128, rt = u >> 4, ks = u & 15;
    const float* s = &W2[(rt * 16 + li) * 256 + ks * 16 + gq];
#pragma unroll
    for (int r = 0; r < 4; ++r) v[r] = s[r];
  } else if (unit < 252) {               // conv_w [150][81] pad to [160][96]
    int u = unit - 192, ct = u / 6, ks = u - ct * 6;
    int row = ct * 16 + li;
#pragma unroll
    for (int r = 0; r < 4; ++r) {
      int col = ks * 16 + gq + r;
      v[r] = (row < 150 && col < 81) ? conv_w[row * 81 + col] : 0.f;
    }
  } else {                               // proj_w [64][150] pad to [64][160]
    int u = unit - 252, dt = u / 10, ct = u - dt * 10;
#pragma unroll
    for (int r = 0; r < 4; ++r) {
      int col = ct * 16 + gq + r;
      v[r] = (col < 150) ? proj_w[(dt * 16 + li) * 150 + col] : 0.f;
    }
  }
  half4 o;
#pragma unroll
  for (int r = 0; r < 4; ++r) o[r] = (half_t)v[r];
  ((half4*)dst)[id] = o;
}

// ---------------------------------------------------------------------------
// k_net: conv -> LN1 -> attention -> LN2 -> FFN -> final LN, one kernel.
// Residual stream lives in registers (res[2][4] f32x4, fragment layout:
// row = channel ct*16+g*4+r, col = token qt*16+li). Tokens written to global
// exactly once (final LN'd, staged via LDS for coalesced 1KB stores).
// 512 threads, 78,256 B dynamic LDS -> 2 blocks/CU.
// LDS pool (bytes):
//   [0,5040)      xs (35x36 padded image, f32)         [phase 0+conv]
//   [5040,31664)  Xh (208x64 f16 swizzled)             [LN1..FFN]
//   [31664,48304) Kb (2 heads x 208 x 20 f16)          [attn]
//   [48304,61872) VT (2 heads x 16 x 212 f16)          [attn]
//   [61872,70064) W1S, [70064,78256) W2S               [FFN]
//   phase0 aliases: WcS@31664 (30,720B), PwS@5040 (20,480B)
//   FFN alias:      Hb@31664 (26,624B)
//   final alias:    OS@5040 (13 tiles x 16 x 68 f32 = 56,576B)
// ---------------------------------------------------------------------------
__global__ __launch_bounds__(512, 4) void k_net(
    const float* __restrict__ x,
    const half_t* __restrict__ WQP, const half_t* __restrict__ WOP,
    const half_t* __restrict__ W1P, const half_t* __restrict__ W2P,
    const half_t* __restrict__ WcP, const half_t* __restrict__ PwP,
    const float* __restrict__ proj_b,
    const float* __restrict__ ln1_g, const float* __restrict__ ln1_b,
    const float* __restrict__ bqkv, const float* __restrict__ bo,
    const float* __restrict__ ln2_g, const float* __restrict__ ln2_b,
    const float* __restrict__ b1, const float* __restrict__ b2,
    const float* __restrict__ tln_g, const float* __restrict__ tln_b,
    float* __restrict__ tokens) {
  extern __shared__ char pool[];
  float* xs = (float*)pool;
  half_t* Xh = (half_t*)(pool + 5040);
  half_t* Kb = (half_t*)(pool + 31664);
  half_t* VT = (half_t*)(pool + 48304);
  half4* W1S = (half4*)(pool + 61872);
  half4* W2S = (half4*)(pool + 70064);
  half4* WcS = (half4*)(pool + 31664);   // phase-0 alias
  half4* PwS = (half4*)(pool + 5040);    // phase-0 alias
  half_t* Hb = (half_t*)(pool + 31664);  // FFN alias
  float* OS = (float*)(pool + 5040);     // final alias

  const int b = blockIdx.x, tid = threadIdx.x;
  const int wv = tid >> 6, ln = tid & 63, g = ln >> 4, li = ln & 15;
  const size_t base = (size_t)b * 12544;

  // res[qi][ct] : residual fragment, token col = (wv+8qi)*16+li,
  // channel row = ct*16+g*4+r
  f32x4 res[2][4];
#pragma unroll
  for (int qi = 0; qi < 2; ++qi)
#pragma unroll
    for (int ct = 0; ct < 4; ++ct) res[qi][ct] = f32x4{0.f, 0.f, 0.f, 0.f};

  // ---- phase 0: stage image + conv/proj weight frags ----
  for (int i = tid; i < 1260; i += 512) xs[i] = 0.f;
  __syncthreads();
  for (int i = tid; i < 784; i += 512) {
    int r = i / 28, c = i - r * 28;
    xs[(r + 4) * 36 + c + 4] = x[b * 784 + i];
  }
  for (int i = tid; i < 3840; i += 512) WcS[i] = ((const half4*)WcP)[i];
  for (int i = tid; i < 2560; i += 512) PwS[i] = ((const half4*)PwP)[i];
  __syncthreads();

  // ---- conv + gelu + proj -> res ----
#pragma unroll
  for (int qi = 0; qi < 2; ++qi) {
    int qt = wv + 8 * qi;
    if (qt < 13) {
      int pp = qt * 16 + li;
      int pc = (pp < 196) ? pp : 195;
      int oy = pc / 14, ox = pc - oy * 14;
      int pbase = (oy * 2) * 36 + ox * 2;
      half4 bf[6];
#pragma unroll
      for (int ks = 0; ks < 6; ++ks) {
#pragma unroll
        for (int r = 0; r < 4; ++r) {
          int tap = ks * 16 + g * 4 + r;   // 0..95
          float v = 0.f;
          if (ks < 5) {
            int ky = tap / 9;
            v = xs[pbase + ky * 27 + tap];
          } else if (tap == 80) {
            v = xs[pbase + 8 * 27 + 80];
          }
          bf[ks][r] = (half_t)v;
        }
      }
      half4 hf[10];
#pragma unroll
      for (int ct = 0; ct < 10; ++ct) {
        f32x4 acc = {0.f, 0.f, 0.f, 0.f};
#pragma unroll
        for (int ks = 0; ks < 6; ++ks) acc = MFMA16(WcS[(ct * 6 + ks) * 64 + ln], bf[ks], acc);
#pragma unroll
        for (int r = 0; r < 4; ++r) hf[ct][r] = (half_t)fast_gelu(acc[r]);
      }
#pragma unroll
      for (int dt = 0; dt < 4; ++dt) {
#pragma unroll
        for (int ct = 0; ct < 10; ++ct)
          res[qi][dt] = MFMA16(PwS[(dt * 10 + ct) * 64 + ln], hf[ct], res[qi][dt]);
        float4 pb4 = *(const float4*)&proj_b[dt * 16 + g * 4];
        res[qi][dt][0] += pb4.x; res[qi][dt][1] += pb4.y;
        res[qi][dt][2] += pb4.z; res[qi][dt][3] += pb4.w;
      }
    }
  }
  __syncthreads();   // conv reads done; xs/WcS/PwS regions now reusable

  // ---- LN1 (in-register, 2-pass) -> Xh ----
  for (int i = tid; i < 768; i += 512) Xh[XH(196 + (i >> 6), i & 63)] = (half_t)0.f;
#pragma unroll
  for (int qi = 0; qi < 2; ++qi) {
    int qt = wv + 8 * qi;
    if (qt < 13) {     // wave-uniform
      float sum = 0.f;
#pragma unroll
      for (int ct = 0; ct < 4; ++ct)
#pragma unroll
        for (int r = 0; r < 4; ++r) sum += res[qi][ct][r];
      sum += __shfl_xor(sum, 16, 64);
      sum += __shfl_xor(sum, 32, 64);
      float mu = sum * 0.015625f;
      float vs = 0.f;
#pragma unroll
      for (int ct = 0; ct < 4; ++ct)
#pragma unroll
        for (int r = 0; r < 4; ++r) { float d = res[qi][ct][r] - mu; vs += d * d; }
      vs += __shfl_xor(vs, 16, 64);
      vs += __shfl_xor(vs, 32, 64);
      float rs = rsqrtf(vs * 0.015625f + 1e-5f);
      int t = qt * 16 + li;
      if (t < 196) {
#pragma unroll
        for (int ct = 0; ct < 4; ++ct) {
          float4 gg = *(const float4*)&ln1_g[ct * 16 + g * 4];
          float4 bb = *(const float4*)&ln1_b[ct * 16 + g * 4];
          half4 o;
          o[0] = (half_t)((res[qi][ct][0] - mu) * rs * gg.x + bb.x);
          o[1] = (half_t)((res[qi][ct][1] - mu) * rs * gg.y + bb.y);
          o[2] = (half_t)((res[qi][ct][2] - mu) * rs * gg.z + bb.z);
          o[3] = (half_t)((res[qi][ct][3] - mu) * rs * gg.w + bb.w);
          *(half4*)&Xh[XH4(t, ct * 4 + g)] = o;
        }
      }
    }
  }
  __syncthreads();

  // ---- attention: 2 head-pair passes, z accumulates into res ----
  for (int p = 0; p < 2; ++p) {
    {
      int rt4 = wv & 3, hh = rt4 & 1;
      bool isK = rt4 < 2;
      int rtg = (isK ? 4 : 8) + 2 * p + hh;
      half4 af[4];
#pragma unroll
      for (int ks = 0; ks < 4; ++ks) af[ks] = ((const half4*)WQP)[(rtg * 4 + ks) * 64 + ln];
      float bias[4];
      int brow = (isK ? 64 : 128) + (2 * p + hh) * 16 + g * 4;
#pragma unroll
      for (int r = 0; r < 4; ++r) bias[r] = bqkv[brow + r];
      int ta = (wv < 4) ? 0 : 7, tz = (wv < 4) ? 7 : 13;
      for (int tt = ta; tt < tz; ++tt) {
        int trow = tt * 16 + li;
        f32x4 acc = {0.f, 0.f, 0.f, 0.f};
#pragma unroll
        for (int ks = 0; ks < 4; ++ks)
          acc = MFMA16(af[ks], *(const half4*)&Xh[XH4(trow, ks * 4 + g)], acc);
        if (isK) {
#pragma unroll
          for (int r = 0; r < 4; ++r)
            Kb[(hh * 208 + trow) * 20 + g * 4 + r] = (half_t)(acc[r] + bias[r]);
        } else {
#pragma unroll
          for (int r = 0; r < 4; ++r)
            VT[(hh * 16 + g * 4 + r) * 212 + trow] = (half_t)(acc[r] + bias[r]);
        }
      }
    }
    half4 qf[2][2];   // scale folds 1/4 * log2(e)
#pragma unroll
    for (int hh = 0; hh < 2; ++hh) {
      half4 aq[4];
#pragma unroll
      for (int ks = 0; ks < 4; ++ks)
        aq[ks] = ((const half4*)WQP)[((2 * p + hh) * 4 + ks) * 64 + ln];
      float qb[4];
#pragma unroll
      for (int r = 0; r < 4; ++r) qb[r] = bqkv[(2 * p + hh) * 16 + g * 4 + r];
#pragma unroll
      for (int qi = 0; qi < 2; ++qi) {
        int qt = wv + 8 * qi;
        if (qt < 13) {
          f32x4 acc = {0.f, 0.f, 0.f, 0.f};
#pragma unroll
          for (int ks = 0; ks < 4; ++ks)
            acc = MFMA16(aq[ks], *(const half4*)&Xh[XH4(qt * 16 + li, ks * 4 + g)], acc);
#pragma unroll
          for (int r = 0; r < 4; ++r)
            qf[qi][hh][r] = (half_t)((acc[r] + qb[r]) * 0.36067376022224085f);
        }
      }
    }
    __syncthreads();
#pragma unroll
    for (int qi = 0; qi < 2; ++qi) {
      int qt = wv + 8 * qi;
      if (qt < 13) {
#pragma unroll
        for (int hh = 0; hh < 2; ++hh) {
          f32x4 s[13];
#pragma unroll
          for (int nt = 0; nt < 13; ++nt) {
            f32x4 zz = {0.f, 0.f, 0.f, 0.f};
            s[nt] = MFMA16(*(const half4*)&Kb[(hh * 208 + nt * 16 + li) * 20 + g * 4],
                           qf[qi][hh], zz);
          }
          if (g > 0) { s[12][0] = -3e38f; s[12][1] = -3e38f; s[12][2] = -3e38f; s[12][3] = -3e38f; }
          float m = -3e38f;
#pragma unroll
          for (int nt = 0; nt < 13; ++nt)
#pragma unroll
            for (int r = 0; r < 4; ++r) m = fmaxf(m, s[nt][r]);
          m = fmaxf(m, __shfl_xor(m, 16, 64));
          m = fmaxf(m, __shfl_xor(m, 32, 64));
          float es = 0.f;
          f32x4 oa = {0.f, 0.f, 0.f, 0.f};
#pragma unroll
          for (int nt = 0; nt < 13; ++nt) {
            half4 pf;
#pragma unroll
            for (int r = 0; r < 4; ++r) {
              float e = EXP2F(s[nt][r] - m);
              es += e;
              pf[r] = (half_t)e;
            }
            half4 va = *(const half4*)&VT[(hh * 16 + li) * 212 + nt * 16 + g * 4];
            oa = MFMA16(va, pf, oa);
          }
          es += __shfl_xor(es, 16, 64);
          es += __shfl_xor(es, 32, 64);
          float inv = 1.0f / es;
          half4 of;
#pragma unroll
          for (int r = 0; r < 4; ++r) of[r] = (half_t)(oa[r] * inv);
          int hglob = 2 * p + hh;
#pragma unroll
          for (int ct = 0; ct < 4; ++ct) {
            half4 wf = ((const half4*)WOP)[(ct * 4 + hglob) * 64 + ln];
            res[qi][ct] = MFMA16(wf, of, res[qi][ct]);
          }
        }
      }
    }
    __syncthreads();
  }
  // + bo
#pragma unroll
  for (int qi = 0; qi < 2; ++qi) {
    int qt = wv + 8 * qi;
    if (qt < 13) {
#pragma unroll
      for (int ct = 0; ct < 4; ++ct) {
        float4 bb = *(const float4*)&bo[ct * 16 + g * 4];
        res[qi][ct][0] += bb.x; res[qi][ct][1] += bb.y;
        res[qi][ct][2] += bb.z; res[qi][ct][3] += bb.w;
      }
    }
  }

  // ---- LN2 -> Xh (t2) ----
#pragma unroll
  for (int qi = 0; qi < 2; ++qi) {
    int qt = wv + 8 * qi;
    if (qt < 13) {
      float sum = 0.f;
#pragma unroll
      for (int ct = 0; ct < 4; ++ct)
#pragma unroll
        for (int r = 0; r < 4; ++r) sum += res[qi][ct][r];
      sum += __shfl_xor(sum, 16, 64);
      sum += __shfl_xor(sum, 32, 64);
      float mu = sum * 0.015625f;
      float vs = 0.f;
#pragma unroll
      for (int ct = 0; ct < 4; ++ct)
#pragma unroll
        for (int r = 0; r < 4; ++r) { float d = res[qi][ct][r] - mu; vs += d * d; }
      vs += __shfl_xor(vs, 16, 64);
      vs += __shfl_xor(vs, 32, 64);
      float rs = rsqrtf(vs * 0.015625f + 1e-5f);
      int t = qt * 16 + li;
      if (t < 196) {
#pragma unroll
        for (int ct = 0; ct < 4; ++ct) {
          float4 gg = *(const float4*)&ln2_g[ct * 16 + g * 4];
          float4 bb = *(const float4*)&ln2_b[ct * 16 + g * 4];
          half4 o;
          o[0] = (half_t)((res[qi][ct][0] - mu) * rs * gg.x + bb.x);
          o[1] = (half_t)((res[qi][ct][1] - mu) * rs * gg.y + bb.y);
          o[2] = (half_t)((res[qi][ct][2] - mu) * rs * gg.z + bb.z);
          o[3] = (half_t)((res[qi][ct][3] - mu) * rs * gg.w + bb.w);
          *(half4*)&Xh[XH4(t, ct * 4 + g)] = o;
        }
      }
    }
  }
  __syncthreads();

  // ---- FFN: 4 chunks of 64 hidden; GEMM2 flipped (A=W2, B=H) -> res ----
  for (int ch = 0; ch < 4; ++ch) {
    for (int i = tid; i < 1024; i += 512) W1S[i] = ((const half4*)W1P)[ch * 1024 + i];
    for (int i = tid; i < 1024; i += 512) {
      int ct = i >> 8, kl = (i >> 6) & 3, l2 = i & 63;
      W2S[i] = ((const half4*)W2P)[(ct * 16 + ch * 4 + kl) * 64 + l2];
    }
    __syncthreads();
    // H = gelu(t2 @ W1^T + b1) -> Hb  (D: col=hidden, row=token)
#pragma unroll
    for (int j = 0; j < 7; ++j) {
      int u = wv + 8 * j;
      if (u < 52) {
        int mt = u >> 2, nt = u & 3;
        f32x4 acc = {0.f, 0.f, 0.f, 0.f};
#pragma unroll
        for (int ks = 0; ks < 4; ++ks)
          acc = MFMA16(*(const half4*)&Xh[XH4(mt * 16 + li, ks * 4 + g)],
                       W1S[(nt * 4 + ks) * 64 + ln], acc);
        float bb = b1[ch * 64 + nt * 16 + li];
#pragma unroll
        for (int r = 0; r < 4; ++r)
          Hb[XH(mt * 16 + g * 4 + r, nt * 16 + li)] = (half_t)fast_gelu(acc[r] + bb);
      }
    }
    __syncthreads();
    // res += W2 @ H  (A=W2 channel rows, B=H token rows -> col=token ✓)
#pragma unroll
    for (int qi = 0; qi < 2; ++qi) {
      int qt = wv + 8 * qi;
      if (qt < 13) {
#pragma unroll
        for (int ct = 0; ct < 4; ++ct)
#pragma unroll
          for (int kl = 0; kl < 4; ++kl)
            res[qi][ct] = MFMA16(W2S[(ct * 4 + kl) * 64 + ln],
                                 *(const half4*)&Hb[XH4(qt * 16 + li, kl * 4 + g)],
                                 res[qi][ct]);
      }
    }
    __syncthreads();
  }
  // + b2
#pragma unroll
  for (int qi = 0; qi < 2; ++qi) {
    int qt = wv + 8 * qi;
    if (qt < 13) {
#pragma unroll
      for (int ct = 0; ct < 4; ++ct) {
        float4 bb = *(const float4*)&b2[ct * 16 + g * 4];
        res[qi][ct][0] += bb.x; res[qi][ct][1] += bb.y;
        res[qi][ct][2] += bb.z; res[qi][ct][3] += bb.w;
      }
    }
  }

  // ---- final LN (tln) -> OS staging -> coalesced write ----
#pragma unroll
  for (int qi = 0; qi < 2; ++qi) {
    int qt = wv + 8 * qi;
    if (qt < 13) {
      float sum = 0.f;
#pragma unroll
      for (int ct = 0; ct < 4; ++ct)
#pragma unroll
        for (int r = 0; r < 4; ++r) sum += res[qi][ct][r];
      sum += __shfl_xor(sum, 16, 64);
      sum += __shfl_xor(sum, 32, 64);
      float mu = sum * 0.015625f;
      float vs = 0.f;
#pragma unroll
      for (int ct = 0; ct < 4; ++ct)
#pragma unroll
        for (int r = 0; r < 4; ++r) { float d = res[qi][ct][r] - mu; vs += d * d; }
      vs += __shfl_xor(vs, 16, 64);
      vs += __shfl_xor(vs, 32, 64);
      float rs = rsqrtf(vs * 0.015625f + 1e-5f);
#pragma unroll
      for (int ct = 0; ct < 4; ++ct) {
        float4 gg = *(const float4*)&tln_g[ct * 16 + g * 4];
        float4 bb = *(const float4*)&tln_b[ct * 16 + g * 4];
        float4 o;
        o.x = (res[qi][ct][0] - mu) * rs * gg.x + bb.x;
        o.y = (res[qi][ct][1] - mu) * rs * gg.y + bb.y;
        o.z = (res[qi][ct][2] - mu) * rs * gg.z + bb.z;
        o.w = (res[qi][ct][3] - mu) * rs * gg.w + bb.w;
        *(float4*)&OS[qt * 1088 + li * 68 + ct * 16 + g * 4] = o;
      }
    }
  }
  __syncthreads();
  for (int i = tid; i < 3328; i += 512) {   // 13 tiles x 256 float4-units
    int tile = i >> 8, rw = (i >> 4) & 15, q = i & 15;
    int t = tile * 16 + rw;
    if (t < 196)
      *(float4*)&tokens[base + (size_t)t * 64 + q * 4] =
          *(const float4*)&OS[tile * 1088 + rw * 68 + q * 4];
  }
}

// ---------------------------------------------------------------------------
// slots: plain load (tln already applied) + slot attention + spmask + classifier
// ---------------------------------------------------------------------------
__global__ __launch_bounds__(256) void k_slots(
    const float* __restrict__ tokens, const float* __restrict__ slot_q,
    const float* __restrict__ cls_w, const float* __restrict__ cls_b,
    const int* __restrict__ use_spmask_p, const int* __restrict__ grid_p,
    float* __restrict__ out) {
  __shared__ float TOK[12544];
  __shared__ float Abuf[12 * 196];
  __shared__ float SQS[12 * 64];
  __shared__ float INV[196];
  __shared__ float VV[64];
  __shared__ float Pv[12];
  __shared__ float M2[12];
  __shared__ float ISN[12];
  __shared__ float ZS[2];

  const int b = blockIdx.x, tid = threadIdx.x;
  const size_t base = (size_t)b * 12544;
  (void)grid_p;

  for (int i = tid; i < 12544; i += 256) {
    int t = i >> 6, c = i & 63;
    TOK[SWi(t, c)] = tokens[base + i];
  }
  __syncthreads();
  if (tid < 196) {
    float ss = 0.f;
#pragma unroll
    for (int q = 0; q < 16; ++q) {
      float4 v = *(const float4*)&TOK[SW4i(tid, q)];
      ss += v.x * v.x + v.y * v.y + v.z * v.z + v.w * v.w;
    }
    INV[tid] = 1.0f / fmaxf(sqrtf(ss), 1e-12f);
  }
  if (tid < 192) {
    int m = tid >> 4, l = tid & 15;
    float ss = 0.f;
#pragma unroll
    for (int c = l; c < 64; c += 16) {
      float v = slot_q[m * 64 + c];
      ss += v * v;
    }
#pragma unroll
    for (int mm = 8; mm; mm >>= 1) ss += __shfl_xor(ss, mm, 64);
    float invq = 1.0f / fmaxf(sqrtf(ss), 1e-12f);
#pragma unroll
    for (int c = l; c < 64; c += 16) SQS[m * 64 + c] = slot_q[m * 64 + c] * invq;
  }
  __syncthreads();
  for (int i = tid; i < 2352; i += 256) {
    int m = i / 196, n = i - m * 196;
    float d = 0.f;
#pragma unroll
    for (int q = 0; q < 16; ++q) {
      float4 tv = *(const float4*)&TOK[SW4i(n, q)];
      float4 sv = *(const float4*)&SQS[m * 64 + q * 4];
      d += tv.x * sv.x + tv.y * sv.y + tv.z * sv.z + tv.w * sv.w;
    }
    Abuf[i] = d * INV[n] * 0.125f;
  }
  __syncthreads();
  const int use_spmask = *use_spmask_p;
  if (tid < 192) {
    int m = tid >> 4, l = tid & 15;
    float* Am = Abuf + m * 196;
    float mx = -1e30f;
    for (int n = l; n < 196; n += 16) mx = fmaxf(mx, Am[n]);
#pragma unroll
    for (int mm = 8; mm; mm >>= 1) mx = fmaxf(mx, __shfl_xor(mx, mm, 64));
    float se = 0.f, mc0 = 0.f, mc1 = 0.f, mc2 = 0.f, mc3 = 0.f;
    for (int n = l; n < 196; n += 16) {
      float e = __expf(Am[n] - mx);
      Am[n] = e;
      se += e;
      int yy = n / 14, xx = n - yy * 14;
      int cell = ((yy >= 7) ? 2 : 0) + ((xx >= 7) ? 1 : 0);
      mc0 += (cell == 0) ? e : 0.f;
      mc1 += (cell == 1) ? e : 0.f;
      mc2 += (cell == 2) ? e : 0.f;
      mc3 += (cell == 3) ? e : 0.f;
    }
#pragma unroll
    for (int mm = 8; mm; mm >>= 1) {
      se += __shfl_xor(se, mm, 64);
      mc0 += __shfl_xor(mc0, mm, 64);
      mc1 += __shfl_xor(mc1, mm, 64);
      mc2 += __shfl_xor(mc2, mm, 64);
      mc3 += __shfl_xor(mc3, mm, 64);
    }
    float invse = 1.0f / se;
    if (use_spmask) {
      int g1 = 0; float bv1 = mc0;
      if (mc1 > bv1) { bv1 = mc1; g1 = 1; }
      if (mc2 > bv1) { bv1 = mc2; g1 = 2; }
      if (mc3 > bv1) { bv1 = mc3; g1 = 3; }
      int g2 = -1; float bv2 = -1e30f;
      if (g1 != 0 && mc0 > bv2) { bv2 = mc0; g2 = 0; }
      if (g1 != 1 && mc1 > bv2) { bv2 = mc1; g2 = 1; }
      if (g1 != 2 && mc2 > bv2) { bv2 = mc2; g2 = 2; }
      if (g1 != 3 && mc3 > bv2) { bv2 = mc3; g2 = 3; }
      float sacc = 0.f;
      for (int n = l; n < 196; n += 16) {
        float a = Am[n] * invse;
        Am[n] = a;
        int yy = n / 14, xx = n - yy * 14;
        int cell = ((yy >= 7) ? 2 : 0) + ((xx >= 7) ? 1 : 0);
        sacc += (cell == g1 || cell == g2) ? a : 0.f;
      }
#pragma unroll
      for (int mm = 8; mm; mm >>= 1) sacc += __shfl_xor(sacc, mm, 64);
      float invs = 1.0f / fmaxf(sacc, 1e-8f);
      float m2acc = 0.f;
      for (int n = l; n < 196; n += 16) {
        int yy = n / 14, xx = n - yy * 14;
        int cell = ((yy >= 7) ? 2 : 0) + ((xx >= 7) ? 1 : 0);
        float a = (cell == g1 || cell == g2) ? (Am[n] * invs) : 0.f;
        Am[n] = a;
        m2acc += a;
      }
#pragma unroll
      for (int mm = 8; mm; mm >>= 1) m2acc += __shfl_xor(m2acc, mm, 64);
      if (l == 0) M2[m] = m2acc;
    } else {
      for (int n = l; n < 196; n += 16) Am[n] *= invse;
      if (l == 0) M2[m] = mx + logf(se);
    }
  }
  __syncthreads();
  if (tid == 0) {
    float mean = 0.f;
    for (int m = 0; m < 12; ++m) mean += M2[m];
    mean *= (1.0f / 12.0f);
    float zmax = -1e30f;
    for (int m = 0; m < 12; ++m) {
      float z = (M2[m] - mean) * 2.0f;
      Pv[m] = z;
      zmax = fmaxf(zmax, z);
    }
    float seP = 0.f;
    for (int m = 0; m < 12; ++m) {
      float e = __expf(Pv[m] - zmax);
      Pv[m] = e;
      seP += e;
    }
    float invP = 1.0f / seP;
    float sump = 0.f;
    for (int m = 0; m < 12; ++m) {
      float p = Pv[m] * invP;
      Pv[m] = p;
      sump += p;
    }
    ZS[0] = sump;
  }
  __syncthreads();
  for (int i = tid; i < 768; i += 256) {
    int m = i >> 6, c = i & 63;
    float a2 = 0.f;
    const float* Am = Abuf + m * 196;
    for (int n = 0; n < 196; ++n) a2 += Am[n] * TOK[SWi(n, c)];
    SQS[m * 64 + c] = a2;
  }
  __syncthreads();
  if (tid < 192) {
    int m = tid >> 4, l = tid & 15;
    float ss = 0.f;
#pragma unroll
    for (int c = l; c < 64; c += 16) {
      float v = SQS[m * 64 + c];
      ss += v * v;
    }
#pragma unroll
    for (int mm = 8; mm; mm >>= 1) ss += __shfl_xor(ss, mm, 64);
    if (l == 0) ISN[m] = 1.0f / fmaxf(sqrtf(ss), 1e-12f);
  }
  __syncthreads();
  if (tid < 64) {
    float v = 0.f;
#pragma unroll
    for (int m = 0; m < 12; ++m) v += Pv[m] * ISN[m] * SQS[m * 64 + tid];
    VV[tid] = v;
  }
  __syncthreads();
  if (tid < 47) {
    float a2 = 0.f;
#pragma unroll
    for (int q = 0; q < 16; ++q) {
      float4 w = *(const float4*)&cls_w[tid * 64 + q * 4];
      float4 v = *(const float4*)&VV[q * 4];
      a2 += w.x * v.x + w.y * v.y + w.z * v.z + w.w * v.w;
    }
    out[(size_t)b * 47 + tid] = a2 + cls_b[tid] * ZS[0];
  }
}

// ---------------------------------------------------------------------------
extern "C" void kernel_launch(void* const* d_in, const int* in_sizes, int n_in,
                              void* d_out, int out_size, void* d_ws, size_t ws_size,
                              hipStream_t stream) {
  (void)n_in; (void)out_size; (void)ws_size;
  const float* x      = (const float*)d_in[0];
  const float* conv_w = (const float*)d_in[1];
  const float* proj_w = (const float*)d_in[2];
  const float* proj_b = (const float*)d_in[3];
  const float* ln1_g  = (const float*)d_in[4];
  const float* ln1_b  = (const float*)d_in[5];
  const float* Wqkv   = (const float*)d_in[6];
  const float* bqkv   = (const float*)d_in[7];
  const float* Wo     = (const float*)d_in[8];
  const float* bo     = (const float*)d_in[9];
  const float* ln2_g  = (const float*)d_in[10];
  const float* ln2_b  = (const float*)d_in[11];
  const float* W1     = (const float*)d_in[12];
  const float* b1     = (const float*)d_in[13];
  const float* W2     = (const float*)d_in[14];
  const float* b2     = (const float*)d_in[15];
  const float* tln_g  = (const float*)d_in[16];
  const float* tln_b  = (const float*)d_in[17];
  const float* slot_q = (const float*)d_in[18];
  const float* cls_w  = (const float*)d_in[19];
  const float* cls_b  = (const float*)d_in[20];
  const int* use_spm  = (const int*)d_in[21];
  const int* spgrid   = (const int*)d_in[22];

  const int B = in_sizes[0] / 784;
  half_t* wsh = (half_t*)d_ws;
  const half_t* WQP = wsh;                     // h4 slots, see k_prepack
  const half_t* WOP = wsh + 3072 * 4;
  const half_t* W1P = wsh + 4096 * 4;
  const half_t* W2P = wsh + 8192 * 4;
  const half_t* WcP = wsh + 12288 * 4;
  const half_t* PwP = wsh + 16128 * 4;
  float* tokens = (float*)((char*)d_ws + 163840);

  k_prepack<<<37, 512, 0, stream>>>(conv_w, proj_w, Wqkv, Wo, W1, W2, wsh);

  const int shnet = 78256;
  (void)hipFuncSetAttribute((const void*)k_net,
                            hipFuncAttributeMaxDynamicSharedMemorySize, shnet);
  k_net<<<B, 512, shnet, stream>>>(x, WQP, WOP, W1P, W2P, WcP, PwP, proj_b,
                                   ln1_g, ln1_b, bqkv, bo, ln2_g, ln2_b,
                                   b1, b2, tln_g, tln_b, tokens);

  k_slots<<<B, 256, 0, stream>>>(tokens, slot_q, cls_w, cls_b, use_spm, spgrid,
                                 (float*)d_out);
}